// Round 7
// baseline (340.868 us; speedup 1.0000x reference)
//
#include <hip/hip_runtime.h>

namespace {

constexpr int D  = 64;    // channels per head
constexpr int T  = 2048;  // sequence length
constexpr int TQ = 64;    // queries per block
constexpr int NT = T / 64;
constexpr float SCL = 0.125f * 1.44269504088896340736f;  // scale^2 * log2(e)

// workspace layout (units: unsigned short):
//  [0, 64*32*8192)             KV tiles: (h*32+kt)*8192 ; K swizzled [s][c] first 4096, V [c][s] next 4096
//  [QP_OFF, QP_OFF+64*32*4096) Q tiles: (h*32+qt)*4096 swizzled [t][c], PRE-SCALED by SCL
constexpr size_t QP_OFF  = (size_t)64 * 32 * 8192;
constexpr size_t WS_NEED = ((size_t)64 * 32 * 8192 + (size_t)64 * 32 * 4096) * 2;  // 50331648 B

typedef __bf16 bf16x8 __attribute__((ext_vector_type(8)));
typedef float  f32x4  __attribute__((ext_vector_type(4)));
typedef unsigned short u16x4 __attribute__((ext_vector_type(4)));
typedef unsigned short u16x8 __attribute__((ext_vector_type(8)));
typedef unsigned int   u32x2 __attribute__((ext_vector_type(2)));

__device__ inline unsigned short f2bf(float f) {   // RNE fp32->bf16, finite inputs
    unsigned int u = __builtin_bit_cast(unsigned int, f);
    u += 0x7FFFu + ((u >> 16) & 1u);
    return (unsigned short)(u >> 16);
}

__device__ inline unsigned int pkbf(float a, float b) {
#if __has_builtin(__builtin_amdgcn_cvt_pk_bf16_f32)
    auto r = __builtin_amdgcn_cvt_pk_bf16_f32(a, b);
    static_assert(sizeof(r) == 4, "cvt_pk_bf16 size");
    return __builtin_bit_cast(unsigned int, r);
#else
    return (unsigned int)f2bf(a) | ((unsigned int)f2bf(b) << 16);
#endif
}

// 64-wide rows, 16B granules XOR-swizzled by ((row>>1)&7). Same image layout
// in LDS (P tile) and in the prepacked global KV/Q tiles, so MFMA fragments
// are 16 contiguous bytes wherever they live.
__device__ inline int frag_off(int row, int c0) {
    int g = (c0 >> 3) ^ ((row >> 1) & 7);
    return row * 64 + g * 8;
}

// ---------------- pre-pass: fp32 -> bf16, swizzled tiles, coalesced writes ----
__global__ __launch_bounds__(256)
void prepass(const float* __restrict__ qkv, unsigned short* __restrict__ ws) {
    const int tile = blockIdx.x, h = blockIdx.y, z = blockIdx.z;
    const int tid = threadIdx.x;
    const float* src = qkv + (size_t)h * 3 * D * T + (size_t)z * D * T + tile * 64;
    __shared__ unsigned short L[4096];

    if (z == 2) {  // V: [c][s] granule-swizzled rows; 16B coalesced stores
        unsigned short* dst = ws + (size_t)(h * 32 + tile) * 8192 + 4096;
        #pragma unroll
        for (int half = 0; half < 2; half++) {
            int idx = half * 256 + tid;        // output granule 0..511
            int row = idx >> 3, g = idx & 7;
            int gg  = g ^ ((row >> 1) & 7);    // source granule
            f32x4 a = *(const f32x4*)(src + (size_t)row * T + gg * 8);
            f32x4 b = *(const f32x4*)(src + (size_t)row * T + gg * 8 + 4);
            u16x8 wv = { f2bf(a[0]), f2bf(a[1]), f2bf(a[2]), f2bf(a[3]),
                         f2bf(b[0]), f2bf(b[1]), f2bf(b[2]), f2bf(b[3]) };
            *(u16x8*)(dst + idx * 8) = wv;     // = dst + row*64 + g*8
        }
    } else {       // Q/K: transpose [c][t] -> swizzled [t][c] via LDS
        const float m = (z == 0) ? SCL : 1.0f;   // fold softmax scale into Q
        const int c0 = (tid >> 4) * 4, s4 = tid & 15;
        float fr[4][4];
        #pragma unroll
        for (int r = 0; r < 4; r++)
            *(f32x4*)fr[r] = *(const f32x4*)(src + (size_t)(c0 + r) * T + s4 * 4);
        #pragma unroll
        for (int j = 0; j < 4; j++) {
            int trow = s4 * 4 + j;
            u16x4 wv = { f2bf(fr[0][j] * m), f2bf(fr[1][j] * m),
                         f2bf(fr[2][j] * m), f2bf(fr[3][j] * m) };
            *(u16x4*)(L + frag_off(trow, c0) + (c0 & 7)) = wv;
        }
        __syncthreads();
        unsigned short* dst = (z == 0)
            ? ws + QP_OFF + (size_t)(h * 32 + tile) * 4096
            : ws + (size_t)(h * 32 + tile) * 8192;
        #pragma unroll
        for (int i = 0; i < 2; i++)
            *(u16x8*)(dst + tid * 16 + i * 8) = *(const u16x8*)(L + tid * 16 + i * 8);
    }
}

// ---------------- main: barrier-free flash attention, 16x16x32 bf16 MFMA ------
// Block = 4 waves. Wave w: sh=w&1 (s-half), th=w>>1 (t-half).
// K/V fragments are read DIRECTLY from the prepacked global tiles (L2-hot:
// head h pinned to XCD h%8, 8 heads x 512 KB = one XCD's L2). LDS holds only
// the wave-private P round-trip -> the K-loop has ZERO __syncthreads; waves
// free-run with no vmcnt-drain barrier stall. 16.5 KB LDS; launch_bounds
// targets 6 blocks/CU (24 waves) for latency hiding.
__global__ __launch_bounds__(256, 6)
void attn_main(const unsigned short* __restrict__ ws, float* __restrict__ out) {
    const int h  = blockIdx.x;      // head pinned to XCD h%8 (id = h + 64*qt)
    const int qt = blockIdx.y;
    const int t0 = qt * TQ;
    const int tid  = threadIdx.x;
    const int lane = tid & 63;
    const int w    = tid >> 6;
    const int sh   = w & 1, th = w >> 1;
    const int ln   = lane & 15, q4 = lane >> 4;

    __shared__ float smem[4096];    // 16 KB: P tile (first 8 KB) during loop,
                                    // O-merge scratch in the epilogue
    __shared__ float lbuf[128];
    unsigned short* Ps = (unsigned short*)smem;   // P^T [t][s], quadrant-disjoint

    // Q fragments (loop-invariant, PRE-SCALED in prepass)
    const unsigned short* qtile = ws + QP_OFF + (size_t)(h * 32 + qt) * 4096;
    bf16x8 bQ[2][2];
    #pragma unroll
    for (int ti = 0; ti < 2; ti++)
        #pragma unroll
        for (int kc = 0; kc < 2; kc++) {
            int t = th * 32 + ti * 16 + ln;
            bQ[ti][kc] = *(const bf16x8*)(qtile + frag_off(t, kc * 32 + q4 * 8));
        }

    // per-lane fragment offsets within one global KV tile (shorts)
    int offK[2][2], offV[4];
    #pragma unroll
    for (int kc = 0; kc < 2; kc++)
        #pragma unroll
        for (int si = 0; si < 2; si++)
            offK[kc][si] = frag_off(sh * 32 + si * 16 + ln, kc * 32 + q4 * 8);
    #pragma unroll
    for (int ci = 0; ci < 4; ci++)
        offV[ci] = 4096 + frag_off(ci * 16 + ln, sh * 32 + q4 * 8);

    // wave-private P LDS addresses
    const unsigned short* bPp[2];
    unsigned int*         pwp[2][2];
    #pragma unroll
    for (int ti = 0; ti < 2; ti++) {
        bPp[ti] = Ps + frag_off(th * 32 + ti * 16 + ln, sh * 32 + q4 * 8);
        #pragma unroll
        for (int si = 0; si < 2; si++) {
            int t = th * 32 + ti * 16 + ln, c0p = sh * 32 + si * 16 + q4 * 4;
            pwp[si][ti] = (unsigned int*)(Ps + frag_off(t, c0p) + (c0p & 7));
        }
    }

    const unsigned short* kv = ws + (size_t)(h * 32) * 8192;  // +8192/iter
    const f32x4 ZF = {0.f, 0.f, 0.f, 0.f};

    f32x4 acc_o[4][2];   // [ci][ti], partial over this wave's s-half
    #pragma unroll
    for (int ci = 0; ci < 4; ci++)
        #pragma unroll
        for (int ti = 0; ti < 2; ti++) acc_o[ci][ti] = ZF;
    float l_acc[2] = {0.f, 0.f};

    #pragma unroll 1
    for (int kt = 0; kt < NT; kt++, kv += 8192) {
        // ---- S^T[s-half][t-half]: fragments straight from L2 ----
        f32x4 acc_s[2][2];
        #pragma unroll
        for (int si = 0; si < 2; si++) {
            bf16x8 aK0 = *(const bf16x8*)(kv + offK[0][si]);
            #pragma unroll
            for (int ti = 0; ti < 2; ti++)
                acc_s[si][ti] = __builtin_amdgcn_mfma_f32_16x16x32_bf16(
                    aK0, bQ[ti][0], ZF, 0, 0, 0);
        }
        #pragma unroll
        for (int si = 0; si < 2; si++) {
            bf16x8 aK1 = *(const bf16x8*)(kv + offK[1][si]);
            #pragma unroll
            for (int ti = 0; ti < 2; ti++)
                acc_s[si][ti] = __builtin_amdgcn_mfma_f32_16x16x32_bf16(
                    aK1, bQ[ti][1], acc_s[si][ti], 0, 0, 0);
        }

        // ---- no-max softmax (Q pre-scaled): P = exp2(acc), lane-private l ----
        #pragma unroll
        for (int si = 0; si < 2; si++)
            #pragma unroll
            for (int ti = 0; ti < 2; ti++) {
                float p0 = __builtin_amdgcn_exp2f(acc_s[si][ti][0]);
                float p1 = __builtin_amdgcn_exp2f(acc_s[si][ti][1]);
                float p2 = __builtin_amdgcn_exp2f(acc_s[si][ti][2]);
                float p3 = __builtin_amdgcn_exp2f(acc_s[si][ti][3]);
                l_acc[ti] += (p0 + p1) + (p2 + p3);
                u32x2 pk = { pkbf(p0, p1), pkbf(p2, p3) };
                *(u32x2*)pwp[si][ti] = pk;      // b64, wave-private quadrant
            }

        // ---- PV: O_partial[64c][t-half]; V fragments straight from L2 ----
        // P written+read by the SAME wave: lgkmcnt ordering only, no barrier.
        bf16x8 bP0 = *(const bf16x8*)bPp[0];
        bf16x8 bP1 = *(const bf16x8*)bPp[1];
        #pragma unroll
        for (int ci = 0; ci < 4; ci++) {
            bf16x8 aV = *(const bf16x8*)(kv + offV[ci]);
            acc_o[ci][0] = __builtin_amdgcn_mfma_f32_16x16x32_bf16(
                aV, bP0, acc_o[ci][0], 0, 0, 0);
            acc_o[ci][1] = __builtin_amdgcn_mfma_f32_16x16x32_bf16(
                aV, bP1, acc_o[ci][1], 0, 0, 0);
        }
    }

    // ---- epilogue: merge s-half partials (O and l) via LDS ----
    __syncthreads();                      // first barrier in the whole kernel
    float* lp = lbuf;
    #pragma unroll
    for (int ti = 0; ti < 2; ti++) {
        float s = l_acc[ti];
        s += __shfl_xor(s, 16, 64);
        s += __shfl_xor(s, 32, 64);
        if (q4 == 0) lp[th * 64 + sh * 32 + ti * 16 + ln] = s;
    }
    if (sh == 0) {
        float* base = smem + th * 2048;
        #pragma unroll
        for (int ci = 0; ci < 4; ci++)
            #pragma unroll
            for (int ti = 0; ti < 2; ti++)
                *(f32x4*)(base + (ci * 2 + ti) * 256 + lane * 4) = acc_o[ci][ti];
    }
    __syncthreads();
    if (sh == 1) {
        float* base = smem + th * 2048;
        float linv[2];
        #pragma unroll
        for (int ti = 0; ti < 2; ti++) {
            int tt = ti * 16 + ln;
            linv[ti] = 1.0f / (lp[th * 64 + tt] + lp[th * 64 + 32 + tt]);
        }
        float* ob = out + (size_t)h * D * T + t0 + th * 32;
        #pragma unroll
        for (int ci = 0; ci < 4; ci++)
            #pragma unroll
            for (int ti = 0; ti < 2; ti++) {
                f32x4 part = *(const f32x4*)(base + (ci * 2 + ti) * 256 + lane * 4);
                #pragma unroll
                for (int r = 0; r < 4; r++) {
                    int c = ci * 16 + q4 * 4 + r;
                    ob[(size_t)c * T + ti * 16 + ln] =
                        (acc_o[ci][ti][r] + part[r]) * linv[ti];
                }
            }
    }
}

// ---------------- fallback (R2 kernel, proven): used if ws too small ----------
__device__ inline bf16x8 frag8(const unsigned short* p, int row, int c0) {
    return *(const bf16x8*)(p + frag_off(row, c0));
}

__global__ __launch_bounds__(256)
void attn_fallback(const float* __restrict__ qkv, float* __restrict__ out) {
    const int h     = blockIdx.y;
    const int t0    = blockIdx.x * TQ;
    const int tid   = threadIdx.x;
    const int lane  = tid & 63;
    const int strip = tid >> 6;
    const int ln    = lane & 15;
    const int q4    = lane >> 4;

    __shared__ unsigned short Qs[TQ * D];
    __shared__ unsigned short Ks[64 * D];
    __shared__ unsigned short Vs[D * 64];
    __shared__ unsigned short Pss[TQ * 64];
    __shared__ float l_lds[TQ];

    const float* qb = qkv + (size_t)h * 3 * D * T;
    const float* kb = qb + (size_t)D * T;
    const float* vb = qb + (size_t)(2 * D) * T;
    const int s4 = tid & 15;
    const int c0 = (tid >> 4) * 4;
    {
        float fr[4][4];
        #pragma unroll
        for (int r = 0; r < 4; r++)
            *(f32x4*)fr[r] = *(const f32x4*)(qb + (size_t)(c0 + r) * T + t0 + s4 * 4);
        #pragma unroll
        for (int j = 0; j < 4; j++) {
            int trow = s4 * 4 + j;
            u16x4 wv = { f2bf(fr[0][j]), f2bf(fr[1][j]), f2bf(fr[2][j]), f2bf(fr[3][j]) };
            *(u16x4*)(Qs + frag_off(trow, c0) + (c0 & 7)) = wv;
        }
    }
    __syncthreads();
    const int arow = strip * 16 + ln;
    const int kg   = q4 * 8;
    const bf16x8 aq0 = frag8(Qs, arow, kg);
    const bf16x8 aq1 = frag8(Qs, arow, 32 + kg);
    f32x4 acc_o[4];
    #pragma unroll
    for (int m = 0; m < 4; m++) acc_o[m] = (f32x4){0.f, 0.f, 0.f, 0.f};
    float l_acc[4] = {0.f, 0.f, 0.f, 0.f};
    constexpr float S2 = 0.125f * 1.44269504088896340736f;
    for (int kt = 0; kt < NT; kt++) {
        const int s0 = kt * 64;
        float kr[4][4], vr[4][4];
        #pragma unroll
        for (int r = 0; r < 4; r++)
            *(f32x4*)kr[r] = *(const f32x4*)(kb + (size_t)(c0 + r) * T + s0 + s4 * 4);
        #pragma unroll
        for (int r = 0; r < 4; r++)
            *(f32x4*)vr[r] = *(const f32x4*)(vb + (size_t)(c0 + r) * T + s0 + s4 * 4);
        __syncthreads();
        #pragma unroll
        for (int j = 0; j < 4; j++) {
            int srow = s4 * 4 + j;
            u16x4 wk = { f2bf(kr[0][j]), f2bf(kr[1][j]), f2bf(kr[2][j]), f2bf(kr[3][j]) };
            *(u16x4*)(Ks + frag_off(srow, c0) + (c0 & 7)) = wk;
        }
        #pragma unroll
        for (int r = 0; r < 4; r++) {
            int row = c0 + r, cc = s4 * 4;
            u16x4 wv = { f2bf(vr[r][0]), f2bf(vr[r][1]), f2bf(vr[r][2]), f2bf(vr[r][3]) };
            *(u16x4*)(Vs + frag_off(row, cc) + (cc & 7)) = wv;
        }
        __syncthreads();
        f32x4 accs[4];
        #pragma unroll
        for (int ns = 0; ns < 4; ns++) {
            bf16x8 b0 = frag8(Ks, ns * 16 + ln, kg);
            bf16x8 b1 = frag8(Ks, ns * 16 + ln, 32 + kg);
            f32x4 z = {0.f, 0.f, 0.f, 0.f};
            z = __builtin_amdgcn_mfma_f32_16x16x32_bf16(aq0, b0, z, 0, 0, 0);
            z = __builtin_amdgcn_mfma_f32_16x16x32_bf16(aq1, b1, z, 0, 0, 0);
            accs[ns] = z;
        }
        #pragma unroll
        for (int ns = 0; ns < 4; ns++) {
            int scol = ns * 16 + ln;
            #pragma unroll
            for (int r = 0; r < 4; r++) {
                float p = __builtin_amdgcn_exp2f(accs[ns][r] * S2);
                l_acc[r] += p;
                int trow = strip * 16 + q4 * 4 + r;
                int g = ((scol >> 3) ^ ((trow >> 1) & 7));
                Pss[trow * 64 + g * 8 + (scol & 7)] = f2bf(p);
            }
        }
        bf16x8 bp0 = frag8(Pss, arow, kg);
        bf16x8 bp1 = frag8(Pss, arow, 32 + kg);
        #pragma unroll
        for (int ms = 0; ms < 4; ms++) {
            bf16x8 av0 = frag8(Vs, ms * 16 + ln, kg);
            bf16x8 av1 = frag8(Vs, ms * 16 + ln, 32 + kg);
            acc_o[ms] = __builtin_amdgcn_mfma_f32_16x16x32_bf16(av0, bp0, acc_o[ms], 0, 0, 0);
            acc_o[ms] = __builtin_amdgcn_mfma_f32_16x16x32_bf16(av1, bp1, acc_o[ms], 0, 0, 0);
        }
    }
    #pragma unroll
    for (int r = 0; r < 4; r++) {
        float s = l_acc[r];
        s += __shfl_xor(s, 1, 64);
        s += __shfl_xor(s, 2, 64);
        s += __shfl_xor(s, 4, 64);
        s += __shfl_xor(s, 8, 64);
        if (ln == 0) l_lds[strip * 16 + q4 * 4 + r] = s;
    }
    const float linv = 1.0f / l_lds[strip * 16 + ln];
    const int tg = t0 + strip * 16 + ln;
    float* ob = out + (size_t)h * D * T;
    #pragma unroll
    for (int ms = 0; ms < 4; ms++)
        #pragma unroll
        for (int r = 0; r < 4; r++) {
            int c = ms * 16 + q4 * 4 + r;
            ob[(size_t)c * T + tg] = acc_o[ms][r] * linv;
        }
}

} // namespace

extern "C" void kernel_launch(void* const* d_in, const int* in_sizes, int n_in,
                              void* d_out, int out_size, void* d_ws, size_t ws_size,
                              hipStream_t stream) {
    const float* qkv = (const float*)d_in[0];
    float* out = (float*)d_out;
    if (ws_size >= WS_NEED) {
        prepass<<<dim3(32, 64, 3), 256, 0, stream>>>(qkv, (unsigned short*)d_ws);
        attn_main<<<dim3(64, 32), 256, 0, stream>>>((const unsigned short*)d_ws, out);
    } else {
        attn_fallback<<<dim3(32, 64), 256, 0, stream>>>(qkv, out);
    }
}

// Round 8
// 251.691 us; speedup vs baseline: 1.3543x; 1.3543x over previous
//
#include <hip/hip_runtime.h>

namespace {

constexpr int D  = 64;    // channels per head
constexpr int T  = 2048;  // sequence length
constexpr int TQ = 64;    // queries per block
constexpr int NT = T / 64;
constexpr float SCL = 0.125f * 1.44269504088896340736f;  // scale^2 * log2(e)

// workspace layout (units: unsigned short):
//  [0, 64*32*8192)             KV tiles: (h*32+kt)*8192 ;
//     K: first 4096 shorts, [s][c] rows of 64, granule-swizzled (quarter w = s rows 16w..16w+16 = contiguous 2 KB)
//     V: next 4096 shorts, QUARTER-BLOCKED: quarter w (2 KB) = rows c of 16 s, granules of 4 shorts swizzled g^((c>>2)&3)
//  [QP_OFF, QP_OFF+64*32*4096) Q tiles: (h*32+qt)*4096 swizzled [t][c], PRE-SCALED by SCL
constexpr size_t QP_OFF  = (size_t)64 * 32 * 8192;
constexpr size_t WS_NEED = ((size_t)64 * 32 * 8192 + (size_t)64 * 32 * 4096) * 2;  // 50331648 B

typedef __bf16 bf16x8 __attribute__((ext_vector_type(8)));
typedef float  f32x4  __attribute__((ext_vector_type(4)));
typedef unsigned short u16x4 __attribute__((ext_vector_type(4)));
typedef unsigned short u16x8 __attribute__((ext_vector_type(8)));
typedef unsigned int   u32x2 __attribute__((ext_vector_type(2)));
typedef short          s16x4 __attribute__((ext_vector_type(4)));

__device__ inline unsigned short f2bf(float f) {   // RNE fp32->bf16, finite inputs
    unsigned int u = __builtin_bit_cast(unsigned int, f);
    u += 0x7FFFu + ((u >> 16) & 1u);
    return (unsigned short)(u >> 16);
}

__device__ inline unsigned int pkbf(float a, float b) {
#if __has_builtin(__builtin_amdgcn_cvt_pk_bf16_f32)
    auto r = __builtin_amdgcn_cvt_pk_bf16_f32(a, b);
    static_assert(sizeof(r) == 4, "cvt_pk_bf16 size");
    return __builtin_bit_cast(unsigned int, r);
#else
    return (unsigned int)f2bf(a) | ((unsigned int)f2bf(b) << 16);
#endif
}

// 64-wide rows, 16B granules XOR-swizzled by ((row>>1)&7) (K/Q images).
__device__ inline int frag_off(int row, int c0) {
    int g = (c0 >> 3) ^ ((row >> 1) & 7);
    return row * 64 + g * 8;
}

__device__ inline void async_cp16(const void* g, void* l) {
    __builtin_amdgcn_global_load_lds(
        (const __attribute__((address_space(1))) unsigned int*)g,
        (__attribute__((address_space(3))) unsigned int*)l, 16, 0, 0);
}

// ---------------- pre-pass: fp32 -> bf16, swizzled tiles, coalesced writes ----
__global__ __launch_bounds__(256)
void prepass(const float* __restrict__ qkv, unsigned short* __restrict__ ws) {
    const int tile = blockIdx.x, h = blockIdx.y, z = blockIdx.z;
    const int tid = threadIdx.x;
    const float* src = qkv + (size_t)h * 3 * D * T + (size_t)z * D * T + tile * 64;
    __shared__ unsigned short L[4096];

    if (z == 2) {  // V: quarter-blocked [wq][c][16s], granule(4sh) swizzle g^((c>>2)&3)
        unsigned short* dst = ws + (size_t)(h * 32 + tile) * 8192 + 4096;
        const int c = tid >> 2, g = tid & 3;
        const int sg = g ^ ((c >> 2) & 3);           // source granule (s-local/4)
        #pragma unroll
        for (int wq = 0; wq < 4; wq++) {
            f32x4 a = *(const f32x4*)(src + (size_t)c * T + wq * 16 + sg * 4);
            u16x4 wv = { f2bf(a[0]), f2bf(a[1]), f2bf(a[2]), f2bf(a[3]) };
            *(u16x4*)(dst + wq * 1024 + tid * 4) = wv;   // coalesced 8B stores
        }
    } else {       // Q/K: transpose [c][t] -> swizzled [t][c] via LDS
        const float m = (z == 0) ? SCL : 1.0f;   // fold softmax scale into Q
        const int c0 = (tid >> 4) * 4, s4 = tid & 15;
        float fr[4][4];
        #pragma unroll
        for (int r = 0; r < 4; r++)
            *(f32x4*)fr[r] = *(const f32x4*)(src + (size_t)(c0 + r) * T + s4 * 4);
        #pragma unroll
        for (int j = 0; j < 4; j++) {
            int trow = s4 * 4 + j;
            u16x4 wv = { f2bf(fr[0][j] * m), f2bf(fr[1][j] * m),
                         f2bf(fr[2][j] * m), f2bf(fr[3][j] * m) };
            *(u16x4*)(L + frag_off(trow, c0) + (c0 & 7)) = wv;
        }
        __syncthreads();
        unsigned short* dst = (z == 0)
            ? ws + QP_OFF + (size_t)(h * 32 + tile) * 4096
            : ws + (size_t)(h * 32 + tile) * 8192;
        #pragma unroll
        for (int i = 0; i < 2; i++)
            *(u16x8*)(dst + tid * 16 + i * 8) = *(const u16x8*)(L + tid * 16 + i * 8);
    }
}

// ---------------- main: barrier-free-loop flash attention ----------------
// Block = 4 waves; wave w owns s-quarter [16w,16w+16), all 64 t.
// S^T D-frag (t=ln, s=q4*4+r) == B-frag of mfma_16x16x16 (n=ln,k=q4*4+r):
// P never leaves registers. Wave-private K/V staging (2+2 KB, dbuf) via
// global_load_lds; explicit lgkmcnt(0)/vmcnt(4) ordering; ZERO __syncthreads
// in the K-loop. Epilogue: XOR-butterfly merge of 4 s-quarter partials.

#define STAGE(J, B)                                                          \
  { const char* g = kvb + (size_t)(J) * 16384;                               \
    char* lk = wbase + (B) * 4096;                                           \
    async_cp16(g,               lk);                                         \
    async_cp16(g + 1024,        lk + 1024);                                  \
    async_cp16(g + 8192,        lk + 2048);                                  \
    async_cp16(g + 8192 + 1024, lk + 3072); }

#define BODY(KT, B, DO_STAGE, WAITIMM)                                       \
  {                                                                          \
    __builtin_amdgcn_s_waitcnt(0xC07F);  /* lgkmcnt(0): WAR guard */         \
    if (DO_STAGE) STAGE((KT) + 1, (B) ^ 1)                                   \
    __builtin_amdgcn_s_waitcnt(WAITIMM); /* vmcnt(N): tile KT landed */      \
    bf16x8 aK0 = *(const bf16x8*)aKp[B][0];                                  \
    bf16x8 aK1 = *(const bf16x8*)aKp[B][1];                                  \
    s16x4 aV0 = *(const s16x4*)aVp[B][0];                                    \
    s16x4 aV1 = *(const s16x4*)aVp[B][1];                                    \
    s16x4 aV2 = *(const s16x4*)aVp[B][2];                                    \
    s16x4 aV3 = *(const s16x4*)aVp[B][3];                                    \
    f32x4 acc_s[4];                                                          \
    _Pragma("unroll")                                                        \
    for (int ti = 0; ti < 4; ti++)                                           \
      acc_s[ti] = __builtin_amdgcn_mfma_f32_16x16x32_bf16(                   \
          aK0, bQ[ti][0], ZF, 0, 0, 0);                                      \
    _Pragma("unroll")                                                        \
    for (int ti = 0; ti < 4; ti++)                                           \
      acc_s[ti] = __builtin_amdgcn_mfma_f32_16x16x32_bf16(                   \
          aK1, bQ[ti][1], acc_s[ti], 0, 0, 0);                               \
    s16x4 bP[4];                                                             \
    _Pragma("unroll")                                                        \
    for (int ti = 0; ti < 4; ti++) {                                         \
      float p0 = __builtin_amdgcn_exp2f(acc_s[ti][0]);                       \
      float p1 = __builtin_amdgcn_exp2f(acc_s[ti][1]);                       \
      float p2 = __builtin_amdgcn_exp2f(acc_s[ti][2]);                       \
      float p3 = __builtin_amdgcn_exp2f(acc_s[ti][3]);                       \
      l_acc[ti] += (p0 + p1) + (p2 + p3);                                    \
      u32x2 pk = { pkbf(p0, p1), pkbf(p2, p3) };                             \
      bP[ti] = __builtin_bit_cast(s16x4, pk);                                \
    }                                                                        \
    _Pragma("unroll")                                                        \
    for (int ti = 0; ti < 4; ti++) {                                         \
      acc_o[0][ti] = __builtin_amdgcn_mfma_f32_16x16x16bf16_1k(              \
          aV0, bP[ti], acc_o[0][ti], 0, 0, 0);                               \
      acc_o[1][ti] = __builtin_amdgcn_mfma_f32_16x16x16bf16_1k(              \
          aV1, bP[ti], acc_o[1][ti], 0, 0, 0);                               \
      acc_o[2][ti] = __builtin_amdgcn_mfma_f32_16x16x16bf16_1k(              \
          aV2, bP[ti], acc_o[2][ti], 0, 0, 0);                               \
      acc_o[3][ti] = __builtin_amdgcn_mfma_f32_16x16x16bf16_1k(              \
          aV3, bP[ti], acc_o[3][ti], 0, 0, 0);                               \
    }                                                                        \
  }

__global__ __launch_bounds__(256, 3)
void attn_main(const unsigned short* __restrict__ ws, float* __restrict__ out) {
    const int h  = blockIdx.x;      // head pinned to XCD h%8 for L2 locality
    const int qt = blockIdx.y;
    const int t0 = qt * TQ;
    const int tid  = threadIdx.x;
    const int lane = tid & 63;
    const int w    = tid >> 6;      // wave id = s-quarter
    const int ln   = lane & 15, q4 = lane >> 4;

    __shared__ char  sbuf[32768];   // 4 waves x (dbuf x (2K K + 2K V)); merge scratch
    __shared__ float lbuf[256];     // l partials [wave][t]
    char* wbase = sbuf + w * 8192;

    // Q fragments (loop-invariant, PRE-SCALED): B-operand rows t, k over c
    const unsigned short* qtile = ws + QP_OFF + (size_t)(h * 32 + qt) * 4096;
    bf16x8 bQ[4][2];
    #pragma unroll
    for (int ti = 0; ti < 4; ti++)
        #pragma unroll
        for (int kc = 0; kc < 2; kc++)
            bQ[ti][kc] = *(const bf16x8*)(qtile + frag_off(ti * 16 + ln, kc * 32 + q4 * 8));

    // wave-private LDS fragment pointers (both buffers)
    const unsigned short* aKp[2][2];
    const unsigned short* aVp[2][4];
    const int vsw = (q4 ^ ((ln >> 2) & 3)) * 4;   // V granule swizzle (ci-invariant)
    #pragma unroll
    for (int b = 0; b < 2; b++) {
        const unsigned short* base = (const unsigned short*)(wbase + b * 4096);
        #pragma unroll
        for (int kc = 0; kc < 2; kc++)
            aKp[b][kc] = base + frag_off(ln, kc * 32 + q4 * 8);
        #pragma unroll
        for (int ci = 0; ci < 4; ci++)
            aVp[b][ci] = base + 1024 + (16 * ci + ln) * 16 + vsw;
    }
    const char* kvb = (const char*)ws + (size_t)(h * 32) * 16384
                      + (size_t)w * 2048 + lane * 16;
    const f32x4 ZF = {0.f, 0.f, 0.f, 0.f};

    f32x4 acc_o[4][4];   // [ci][ti], partial over this wave's s-quarter
    #pragma unroll
    for (int ci = 0; ci < 4; ci++)
        #pragma unroll
        for (int ti = 0; ti < 4; ti++) acc_o[ci][ti] = ZF;
    float l_acc[4] = {0.f, 0.f, 0.f, 0.f};

    STAGE(0, 0)                      // prologue: tile 0 -> buf 0

    #pragma unroll 1
    for (int m = 0; m < 15; m++) {   // kt = 0..29
        BODY(2 * m,     0, 1, 0x0F74)
        BODY(2 * m + 1, 1, 1, 0x0F74)
    }
    BODY(30, 0, 1, 0x0F74)           // stages tile 31
    BODY(31, 1, 0, 0x0F70)           // vmcnt(0): last tile fully landed

    // ---- epilogue: XOR-butterfly merge of 4 s-quarter partials ----
    __syncthreads();                 // first barrier of the kernel
    #pragma unroll
    for (int ti = 0; ti < 4; ti++) { // l: reduce over q4, publish per-wave
        float s = l_acc[ti];
        s += __shfl_xor(s, 16, 64);
        s += __shfl_xor(s, 32, 64);
        if (q4 == 0) lbuf[w * 64 + ti * 16 + ln] = s;
    }
    float* slots = (float*)sbuf;     // region[w] = 8 KB (2048 floats)
    // round 1: exchange with w^1 on bit0
    #pragma unroll
    for (int q = 0; q < 4; q++)
        if ((q ^ w) & 1) {
            float* dst = slots + w * 2048 + (q >> 1) * 1024;
            #pragma unroll
            for (int ti = 0; ti < 4; ti++)
                *(f32x4*)(dst + ti * 256 + lane * 4) = acc_o[q][ti];
        }
    __syncthreads();
    #pragma unroll
    for (int q = 0; q < 4; q++)
        if (!((q ^ w) & 1)) {
            const float* srcp = slots + (w ^ 1) * 2048 + (q >> 1) * 1024;
            #pragma unroll
            for (int ti = 0; ti < 4; ti++)
                acc_o[q][ti] += *(const f32x4*)(srcp + ti * 256 + lane * 4);
        }
    __syncthreads();
    // round 2: exchange with w^2 on bit1
    #pragma unroll
    for (int q = 0; q < 4; q++)
        if (((q ^ w) & 3) == 2) {
            float* dst = slots + w * 2048;
            #pragma unroll
            for (int ti = 0; ti < 4; ti++)
                *(f32x4*)(dst + ti * 256 + lane * 4) = acc_o[q][ti];
        }
    __syncthreads();
    #pragma unroll
    for (int q = 0; q < 4; q++)
        if (q == w) {
            const float* srcp = slots + (w ^ 2) * 2048;
            float linv[4];
            #pragma unroll
            for (int ti = 0; ti < 4; ti++) {
                int tt = ti * 16 + ln;
                linv[ti] = 1.0f / (lbuf[tt] + lbuf[64 + tt] +
                                   lbuf[128 + tt] + lbuf[192 + tt]);
                acc_o[q][ti] += *(const f32x4*)(srcp + ti * 256 + lane * 4);
            }
            float* ob = out + (size_t)h * D * T + t0;
            #pragma unroll
            for (int ti = 0; ti < 4; ti++)
                #pragma unroll
                for (int rr = 0; rr < 4; rr++) {
                    int c = 16 * w + q4 * 4 + rr;
                    ob[(size_t)c * T + ti * 16 + ln] = acc_o[q][ti][rr] * linv[ti];
                }
        }
}

// ---------------- fallback (R2 kernel, proven): used if ws too small ----------
__device__ inline bf16x8 frag8(const unsigned short* p, int row, int c0) {
    return *(const bf16x8*)(p + frag_off(row, c0));
}

__global__ __launch_bounds__(256)
void attn_fallback(const float* __restrict__ qkv, float* __restrict__ out) {
    const int h     = blockIdx.y;
    const int t0    = blockIdx.x * TQ;
    const int tid   = threadIdx.x;
    const int lane  = tid & 63;
    const int strip = tid >> 6;
    const int ln    = lane & 15;
    const int q4    = lane >> 4;

    __shared__ unsigned short Qs[TQ * D];
    __shared__ unsigned short Ks[64 * D];
    __shared__ unsigned short Vs[D * 64];
    __shared__ unsigned short Pss[TQ * 64];
    __shared__ float l_lds[TQ];

    const float* qb = qkv + (size_t)h * 3 * D * T;
    const float* kb = qb + (size_t)D * T;
    const float* vb = qb + (size_t)(2 * D) * T;
    const int s4 = tid & 15;
    const int c0 = (tid >> 4) * 4;
    {
        float fr[4][4];
        #pragma unroll
        for (int r = 0; r < 4; r++)
            *(f32x4*)fr[r] = *(const f32x4*)(qb + (size_t)(c0 + r) * T + t0 + s4 * 4);
        #pragma unroll
        for (int j = 0; j < 4; j++) {
            int trow = s4 * 4 + j;
            u16x4 wv = { f2bf(fr[0][j]), f2bf(fr[1][j]), f2bf(fr[2][j]), f2bf(fr[3][j]) };
            *(u16x4*)(Qs + frag_off(trow, c0) + (c0 & 7)) = wv;
        }
    }
    __syncthreads();
    const int arow = strip * 16 + ln;
    const int kg   = q4 * 8;
    const bf16x8 aq0 = frag8(Qs, arow, kg);
    const bf16x8 aq1 = frag8(Qs, arow, 32 + kg);
    f32x4 acc_o[4];
    #pragma unroll
    for (int m = 0; m < 4; m++) acc_o[m] = (f32x4){0.f, 0.f, 0.f, 0.f};
    float l_acc[4] = {0.f, 0.f, 0.f, 0.f};
    constexpr float S2 = 0.125f * 1.44269504088896340736f;
    for (int kt = 0; kt < NT; kt++) {
        const int s0 = kt * 64;
        float kr[4][4], vr[4][4];
        #pragma unroll
        for (int r = 0; r < 4; r++)
            *(f32x4*)kr[r] = *(const f32x4*)(kb + (size_t)(c0 + r) * T + s0 + s4 * 4);
        #pragma unroll
        for (int r = 0; r < 4; r++)
            *(f32x4*)vr[r] = *(const f32x4*)(vb + (size_t)(c0 + r) * T + s0 + s4 * 4);
        __syncthreads();
        #pragma unroll
        for (int j = 0; j < 4; j++) {
            int srow = s4 * 4 + j;
            u16x4 wk = { f2bf(kr[0][j]), f2bf(kr[1][j]), f2bf(kr[2][j]), f2bf(kr[3][j]) };
            *(u16x4*)(Ks + frag_off(srow, c0) + (c0 & 7)) = wk;
        }
        #pragma unroll
        for (int r = 0; r < 4; r++) {
            int row = c0 + r, cc = s4 * 4;
            u16x4 wv = { f2bf(vr[r][0]), f2bf(vr[r][1]), f2bf(vr[r][2]), f2bf(vr[r][3]) };
            *(u16x4*)(Vs + frag_off(row, cc) + (cc & 7)) = wv;
        }
        __syncthreads();
        f32x4 accs[4];
        #pragma unroll
        for (int ns = 0; ns < 4; ns++) {
            bf16x8 b0 = frag8(Ks, ns * 16 + ln, kg);
            bf16x8 b1 = frag8(Ks, ns * 16 + ln, 32 + kg);
            f32x4 z = {0.f, 0.f, 0.f, 0.f};
            z = __builtin_amdgcn_mfma_f32_16x16x32_bf16(aq0, b0, z, 0, 0, 0);
            z = __builtin_amdgcn_mfma_f32_16x16x32_bf16(aq1, b1, z, 0, 0, 0);
            accs[ns] = z;
        }
        #pragma unroll
        for (int ns = 0; ns < 4; ns++) {
            int scol = ns * 16 + ln;
            #pragma unroll
            for (int r = 0; r < 4; r++) {
                float p = __builtin_amdgcn_exp2f(accs[ns][r] * S2);
                l_acc[r] += p;
                int trow = strip * 16 + q4 * 4 + r;
                int g = ((scol >> 3) ^ ((trow >> 1) & 7));
                Pss[trow * 64 + g * 8 + (scol & 7)] = f2bf(p);
            }
        }
        bf16x8 bp0 = frag8(Pss, arow, kg);
        bf16x8 bp1 = frag8(Pss, arow, 32 + kg);
        #pragma unroll
        for (int ms = 0; ms < 4; ms++) {
            bf16x8 av0 = frag8(Vs, ms * 16 + ln, kg);
            bf16x8 av1 = frag8(Vs, ms * 16 + ln, 32 + kg);
            acc_o[ms] = __builtin_amdgcn_mfma_f32_16x16x32_bf16(av0, bp0, acc_o[ms], 0, 0, 0);
            acc_o[ms] = __builtin_amdgcn_mfma_f32_16x16x32_bf16(av1, bp1, acc_o[ms], 0, 0, 0);
        }
    }
    #pragma unroll
    for (int r = 0; r < 4; r++) {
        float s = l_acc[r];
        s += __shfl_xor(s, 1, 64);
        s += __shfl_xor(s, 2, 64);
        s += __shfl_xor(s, 4, 64);
        s += __shfl_xor(s, 8, 64);
        if (ln == 0) l_lds[strip * 16 + q4 * 4 + r] = s;
    }
    const float linv = 1.0f / l_lds[strip * 16 + ln];
    const int tg = t0 + strip * 16 + ln;
    float* ob = out + (size_t)h * D * T;
    #pragma unroll
    for (int ms = 0; ms < 4; ms++)
        #pragma unroll
        for (int r = 0; r < 4; r++) {
            int c = ms * 16 + q4 * 4 + r;
            ob[(size_t)c * T + tg] = acc_o[ms][r] * linv;
        }
}

} // namespace

extern "C" void kernel_launch(void* const* d_in, const int* in_sizes, int n_in,
                              void* d_out, int out_size, void* d_ws, size_t ws_size,
                              hipStream_t stream) {
    const float* qkv = (const float*)d_in[0];
    float* out = (float*)d_out;
    if (ws_size >= WS_NEED) {
        prepass<<<dim3(32, 64, 3), 256, 0, stream>>>(qkv, (unsigned short*)d_ws);
        attn_main<<<dim3(64, 32), 256, 0, stream>>>((const unsigned short*)d_ws, out);
    } else {
        attn_fallback<<<dim3(32, 64), 256, 0, stream>>>(qkv, out);
    }
}